// Round 17
// baseline (443.736 us; speedup 1.0000x reference)
//
#include <hip/hip_runtime.h>
#include <hip/hip_fp16.h>
#include <math.h>

#define M_TRAIN 100000
#define NQ 2048
#define DIM 128
#define KNN 16
#define NCLS 10

// Subsample for tau: every 16th train point; padded to 6272 = 49 * 128.
#define S_STRIDE 16
#define S_CNT (M_TRAIN / S_STRIDE)     // 6250
#define S_PAD 6272
#define SCH 49
#define SPC 128
#define TT 64
#define MQ 128
#define QSTR 136                       // LDS row stride in shorts (128 + 8 pad)

// Filter: one block = 64 queries x 128 train rows, one-shot (high TLP).
#define CAP 768
#define NTILE 784                      // ceil(100000/128) tiles over FULL train
#define NTR 128                        // train rows per block
#define NQT 64                         // queries per block
#define MARGIN 3.0f                    // proven in rounds 4-5/8
#define SLACK 7.0f                     // 2*(MARGIN + fp16 quant 0.25) rounded up

using bfrag = __attribute__((ext_vector_type(8))) short;
using cfrag = __attribute__((ext_vector_type(4))) float;

__device__ __forceinline__ bool better(float d1, int i1, float d2, int i2) {
    return (d1 < d2) || (d1 == d2 && i1 < i2);
}

__device__ __forceinline__ unsigned pack_bf16(float a, float b) {
    unsigned ua = __float_as_uint(a), ub = __float_as_uint(b);
    ua += 0x7fffu + ((ua >> 16) & 1u);   // RNE
    ub += 0x7fffu + ((ub >> 16) & 1u);
    return (ua >> 16) | (ub & 0xffff0000u);
}

__device__ __forceinline__ bfrag pack_bf16x8(const float* p) {
    union { unsigned u[4]; bfrag f; } r;
    r.u[0] = pack_bf16(p[0], p[1]);
    r.u[1] = pack_bf16(p[2], p[3]);
    r.u[2] = pack_bf16(p[4], p[5]);
    r.u[3] = pack_bf16(p[6], p[7]);
    return r.f;
}

// Insert v into the sorted-ascending 16-entry register list (set semantics:
// scan order does not affect the final 16-smallest set).
__device__ __forceinline__ void ins16(float (&bd)[KNN], float v) {
    if (v < bd[KNN - 1]) {
        bd[KNN - 1] = v;
        #pragma unroll
        for (int j = KNN - 1; j >= 1; --j)
            if (bd[j] < bd[j - 1]) { float t = bd[j]; bd[j] = bd[j - 1]; bd[j - 1] = t; }
    }
}

// ---------------------------------------------------------------------------
// Kernel 0: squared norms, one wave per row. Also zeroes cnt (folded dispatch).
__global__ void knn_norms(const float* __restrict__ train,
                          const float* __restrict__ x,
                          float* __restrict__ t2, float* __restrict__ x2,
                          int* __restrict__ cnt) {
    int gid = blockIdx.x * blockDim.x + threadIdx.x;
    if (gid < NQ) cnt[gid] = 0;
    int gw = gid >> 6;
    int lane = threadIdx.x & 63;
    if (gw >= M_TRAIN + NQ) return;
    const float* r = (gw < M_TRAIN) ? (train + (size_t)gw * DIM)
                                    : (x + (size_t)(gw - M_TRAIN) * DIM);
    float a = r[lane];
    float b = r[lane + 64];
    float s = a * a + b * b;
    #pragma unroll
    for (int off = 32; off > 0; off >>= 1)
        s += __shfl_down(s, off, 64);
    if (lane == 0) {
        if (gw < M_TRAIN) t2[gw] = s; else x2[gw - M_TRAIN] = s;
    }
}

// ---------------------------------------------------------------------------
// Kernel 1: MFMA (bf16) approx-d2 over the stride-16 subsample -> fp16 matrix.
// A-frags packed in-register from fp32 x (bit-identical); no Q LDS staging.
__global__ __launch_bounds__(256, 3)
void knn_sub_mfma(const float* __restrict__ x, const float* __restrict__ train,
                  const float* __restrict__ t2, const float* __restrict__ x2,
                  __half* __restrict__ dsub) {
    __shared__ short T[TT * QSTR];
    __shared__ float t2h[TT];
    int tid = threadIdx.x;
    int w = tid >> 6, lane = tid & 63;
    int rquad = lane >> 4, rcol = lane & 15;
    int qBase = blockIdx.y * MQ;
    int cBase = blockIdx.x * SPC;

    // A-frags for this wave's 32 query rows, packed from fp32 x (L2-hot).
    bfrag A[2][4];
    #pragma unroll
    for (int rt = 0; rt < 2; ++rt) {
        int qr = qBase + w * 32 + rt * 16 + rcol;
        #pragma unroll
        for (int ks = 0; ks < 4; ++ks)
            A[rt][ks] = pack_bf16x8(&x[(size_t)qr * DIM + ks * 32 + rquad * 8]);
    }

    float x2r[2][4];
    #pragma unroll
    for (int rt = 0; rt < 2; ++rt)
        #pragma unroll
        for (int reg = 0; reg < 4; ++reg)
            x2r[rt][reg] = x2[qBase + w * 32 + rt * 16 + rquad * 4 + reg];

    const cfrag zero4 = {0.f, 0.f, 0.f, 0.f};
    for (int t = 0; t < 2; ++t) {
        __syncthreads();
        int sBase = cBase + t * TT;
        #pragma unroll
        for (int it = 0; it < 8; ++it) {
            int f = it * 256 + tid;
            int row = f >> 5, c4 = f & 31;
            int sj = sBase + row;
            bool ok = sj < S_CNT;
            float4 v = ok ? ((const float4*)train)[(size_t)sj * S_STRIDE * (DIM / 4) + c4]
                          : make_float4(0.f, 0.f, 0.f, 0.f);
            uint2 p; p.x = pack_bf16(v.x, v.y); p.y = pack_bf16(v.z, v.w);
            *(uint2*)&T[row * QSTR + c4 * 4] = p;
        }
        if (tid < TT) {
            int sj = sBase + tid;
            t2h[tid] = (sj < S_CNT) ? t2[(size_t)sj * S_STRIDE] : 1e30f;
        }
        __syncthreads();

        cfrag acc[2][4];
        #pragma unroll
        for (int ks = 0; ks < 4; ++ks) {
            bfrag B[4];
            #pragma unroll
            for (int ct = 0; ct < 4; ++ct) {
                int n = ct * 16 + rcol;
                B[ct] = *(const bfrag*)&T[n * QSTR + ks * 32 + rquad * 8];
            }
            #pragma unroll
            for (int rt = 0; rt < 2; ++rt)
                #pragma unroll
                for (int ct = 0; ct < 4; ++ct)
                    acc[rt][ct] = (ks == 0)
                        ? __builtin_amdgcn_mfma_f32_16x16x32_bf16(A[rt][0], B[ct], zero4, 0, 0, 0)
                        : __builtin_amdgcn_mfma_f32_16x16x32_bf16(A[rt][ks], B[ct], acc[rt][ct], 0, 0, 0);
        }

        float th[4];
        #pragma unroll
        for (int ct = 0; ct < 4; ++ct) th[ct] = t2h[ct * 16 + rcol];
        #pragma unroll
        for (int rt = 0; rt < 2; ++rt)
            #pragma unroll
            for (int ct = 0; ct < 4; ++ct)
                #pragma unroll
                for (int reg = 0; reg < 4; ++reg) {
                    float d2 = x2r[rt][reg] + th[ct] - 2.f * acc[rt][ct][reg];
                    int qrow = qBase + w * 32 + rt * 16 + rquad * 4 + reg;
                    int col = sBase + ct * 16 + rcol;
                    dsub[(size_t)qrow * S_PAD + col] = __float2half_rn(d2);
                }
    }
}

// ---------------------------------------------------------------------------
// Kernel 2: tau[q] = 16th-smallest value of dsub row q (values only).
// Vectorized uint4 scan (round-15 proven) + barrier-free tournament + merge.
__global__ __launch_bounds__(256)
void knn_select(const __half* __restrict__ dsub, float* __restrict__ tau) {
    __shared__ float wk[64];
    int q = blockIdx.x, tid = threadIdx.x;
    int w = tid >> 6, lane = tid & 63;

    float bd[KNN];
    #pragma unroll
    for (int j = 0; j < KNN; ++j) bd[j] = 3.4e38f;

    const uint4* dv = (const uint4*)(dsub + (size_t)q * S_PAD);  // 784 vec8
    #pragma unroll 1
    for (int v = tid; v < S_PAD / 8; v += 256) {
        uint4 pk = dv[v];
        unsigned wd[4] = {pk.x, pk.y, pk.z, pk.w};
        #pragma unroll
        for (int e = 0; e < 4; ++e) {
            ins16(bd, __half2float(__ushort_as_half((unsigned short)(wd[e] & 0xFFFFu))));
            ins16(bd, __half2float(__ushort_as_half((unsigned short)(wd[e] >> 16))));
        }
    }

    // Per-wave 16-smallest (sorted output), no barriers.
    #pragma unroll 1
    for (int sel = 0; sel < KNN; ++sel) {
        float mv = bd[0]; int ml = lane;
        #pragma unroll
        for (int off = 32; off > 0; off >>= 1) {
            float ov = __shfl_down(mv, off, 64);
            int   ol = __shfl_down(ml, off, 64);
            if (ov < mv || (ov == mv && ol < ml)) { mv = ov; ml = ol; }
        }
        mv = __shfl(mv, 0, 64);
        ml = __shfl(ml, 0, 64);
        if (lane == 0) wk[w * KNN + sel] = mv;
        if (lane == ml) {
            #pragma unroll
            for (int j = 0; j < KNN - 1; ++j) bd[j] = bd[j + 1];
            bd[KNN - 1] = 3.4e38f;
        }
    }
    __syncthreads();
    // Rank merge of 4 sorted 16-lists -> exact 16th smallest value.
    if (tid < 64) {
        float v = wk[tid];
        int rank = 0;
        #pragma unroll 8
        for (int j = 0; j < 64; ++j) {
            float u = wk[j];
            if (u < v || (u == v && j < tid)) ++rank;
        }
        if (rank == KNN - 1) tau[q] = v;
    }
}

// ---------------------------------------------------------------------------
// Kernel 3 (tiny): pack x -> linear bf16 xb. Runs AFTER knn_select (xb
// aliases the then-dead dsub tail). 512 blocks, ~3us. Same RNE pack ->
// A-frags bit-identical to the old convert-produced xb.
__global__ __launch_bounds__(256)
void knn_pack_x(const float* __restrict__ x, unsigned int* __restrict__ xb) {
    int gid = blockIdx.x * 256 + threadIdx.x;      // 131072 threads
    int row = gid >> 6, lane = gid & 63;
    float2 v = ((const float2*)x)[(size_t)row * 64 + lane];
    xb[(size_t)row * 64 + lane] = pack_bf16(v.x, v.y);
}

// ---------------------------------------------------------------------------
// Kernel 4: one-shot bf16 MFMA filter (64 queries x 128 train rows, K=128).
// Round-17 FIX of round-16's correctness bug: the staging loop wrote only
// 16 KB of the 32 KB tile (8 iters x 256 thr x 8 B; rows 64..127 were stale
// garbage -> absmax 9.0). Now 16 iterations: f in [0,4096), row = f>>5
// covers all 128 rows, 256x16x8 = 32768 B. Everything else unchanged:
// fp32 train -> bf16 packed directly into the XOR-swizzled LDS layout
// (same RNE pack + same swizzle bits as the old convert+DMA path ->
// LDS bytes bit-identical; read side untouched). ONE dispatch, 784 tiles.
__global__ __launch_bounds__(256, 5)
void knn_filter14(const unsigned int* __restrict__ xbb,
                  const float* __restrict__ train,
                  const float* __restrict__ t2, const float* __restrict__ x2,
                  const float* __restrict__ tau,
                  int* __restrict__ buf_i, unsigned short* __restrict__ buf_h,
                  int* __restrict__ cnt) {
    __shared__ __align__(16) short T[NTR * DIM];   // 32768 B, single buffer
    int tid = threadIdx.x;
    int w = tid >> 6, lane = tid & 63;
    int rquad = lane >> 4, rcol = lane & 15;

    // XCD-affinity decode (proven): same-tile q-blocks share an XCD.
    // 25088 = 8 xcd * 32 qb * 98; nch = xcd + 8*t covers 0..783 exactly.
    int bid = blockIdx.x;
    int xcd = bid & 7, r = bid >> 3;
    int qb = r & 31;
    int nch = xcd + 8 * (r >> 5);          // 0..783, tile index over FULL train
    int qBase = qb * NQT;
    int tbase = nch * NTR;                 // global train row base of tile

    // Stage tile: fp32 train -> bf16, swizzled ds_write (replaces DMA+tb).
    // 16 iters x 256 thr: f in [0,4096), row = f>>5 in [0,128), seg = f&31.
    // Each iter covers 8 rows; 32-lane groups read 512B fp32 rows coalesced.
    // Swizzle byte ^= (row&7)<<4 matches the read-side XOR ((tbase+row)&7
    // == row&7 since tiles are 128-aligned).
    #pragma unroll
    for (int it = 0; it < 16; ++it) {
        int f = it * 256 + tid;
        int row = f >> 5, seg = f & 31;
        int g = tbase + row;
        float4 v = (g < M_TRAIN)
            ? ((const float4*)train)[(size_t)g * (DIM / 4) + seg]
            : make_float4(0.f, 0.f, 0.f, 0.f);
        uint2 p; p.x = pack_bf16(v.x, v.y); p.y = pack_bf16(v.z, v.w);
        int off = (seg * 8) ^ ((row & 7) << 4);
        *(uint2*)((char*)T + row * 256 + off) = p;
    }

    // A-frags: direct bf16 loads from xb (overlap staging latency).
    bfrag A[4];
    int qrow = qBase + w * 16 + rcol;
    const char* xrow = (const char*)xbb + (size_t)qrow * 256;
    #pragma unroll
    for (int ks = 0; ks < 4; ++ks)
        A[ks] = *(const bfrag*)(xrow + ks * 64 + rquad * 16);

    float RC[4], x2q[4];
    #pragma unroll
    for (int reg = 0; reg < 4; ++reg) {
        int q = qBase + w * 16 + rquad * 4 + reg;
        x2q[reg] = x2[q];
        RC[reg] = 0.5f * (x2q[reg] - tau[q] - MARGIN);
    }
    float th[8];
    #pragma unroll
    for (int ct = 0; ct < 8; ++ct)
        th[ct] = 0.5f * t2[tbase + ct * 16 + rcol];
    __syncthreads();                       // drains ds_writes + joins waves

    // Swizzled B reads: row = ct*16+rcol; byte col XOR'd with (rcol&7)<<4.
    int swz = (rcol & 7) << 4;
    int cs[4];
    #pragma unroll
    for (int ks = 0; ks < 4; ++ks)
        cs[ks] = (ks * 64 + rquad * 16) ^ swz;

    const cfrag zero4 = {0.f, 0.f, 0.f, 0.f};
    cfrag acc[8];
    #pragma unroll
    for (int ks = 0; ks < 4; ++ks)
        #pragma unroll
        for (int ct = 0; ct < 8; ++ct) {
            const bfrag B = *(const bfrag*)((const char*)T + (ct * 16 + rcol) * 256 + cs[ks]);
            acc[ct] = (ks == 0)
                ? __builtin_amdgcn_mfma_f32_16x16x32_bf16(A[0], B, zero4, 0, 0, 0)
                : __builtin_amdgcn_mfma_f32_16x16x32_bf16(A[ks], B, acc[ct], 0, 0, 0);
        }

    // ---- Sparse per-lane epilogue (round-11 proven) ----
    unsigned okm = 0;
    #pragma unroll
    for (int ct = 0; ct < 8; ++ct)
        if (tbase + ct * 16 + rcol < M_TRAIN) okm |= (1u << ct);

    unsigned m8[4];
    #pragma unroll
    for (int reg = 0; reg < 4; ++reg) {
        unsigned m = 0;
        #pragma unroll
        for (int ct = 0; ct < 8; ++ct)
            if (acc[ct][reg] >= RC[reg] + th[ct]) m |= (1u << ct);
        m8[reg] = m & okm;
    }

    int slotR[4];
    #pragma unroll
    for (int reg = 0; reg < 4; ++reg)
        if (m8[reg])
            slotR[reg] = atomicAdd(&cnt[qBase + w * 16 + rquad * 4 + reg],
                                   __popc(m8[reg]));

    #pragma unroll
    for (int reg = 0; reg < 4; ++reg) {
        unsigned m = m8[reg];
        if (m) {
            int q = qBase + w * 16 + rquad * 4 + reg;
            size_t qoff = (size_t)q * CAP;
            int s0 = slotR[reg];
            #pragma unroll
            for (int ct = 0; ct < 8; ++ct)
                if (m & (1u << ct)) {
                    int slot = s0 + __popc(m & ((1u << ct) - 1));
                    if (slot < CAP) {
                        buf_i[qoff + slot] = tbase + ct * 16 + rcol;
                        float d2a = x2q[reg] + 2.f * th[ct] - 2.f * acc[ct][reg];
                        buf_h[qoff + slot] = __half_as_ushort(__float2half_rn(d2a));
                    }
                }
        }
    }
}

// ---------------------------------------------------------------------------
// Kernel 5: approx-pruned exact re-rank + weighted vote.
// Phase A: 16th-smallest approx d2 (per-wave tournament + 64-wide rank merge)
// Phase B: compact candidates with d2a <= kth + SLACK (provably contains the
//          exact top-16 given |d2a - d2| <= MARGIN + fp16 quant)
// Phase C: exact fp32 gather ONLY for kept candidates (4-5x fewer rows)
// Phase D: fully parallel rank-scatter selection (no serial 16-round chain)
__global__ __launch_bounds__(256)
void knn_final(const float* __restrict__ x,
               const float* __restrict__ train,
               const float* __restrict__ t2v,
               const float* __restrict__ x2v,
               const int* __restrict__ buf_i,
               const __half* __restrict__ buf_h,
               const int* __restrict__ cnt,
               const int* __restrict__ labels,
               float* __restrict__ out) {
    __shared__ float sd[CAP];
    __shared__ int   si[CAP];
    __shared__ int   keep[CAP];
    __shared__ float wk[64];
    __shared__ int   kr[KNN];
    __shared__ float sthr;
    __shared__ int   smcnt;
    int q = blockIdx.x;
    int tid = threadIdx.x;
    int w = tid >> 6, lane = tid & 63;
    int grp = lane >> 4, sub = lane & 15;
    int n = cnt[q]; if (n > CAP) n = CAP;
    if (tid == 0) smcnt = 0;
    if (tid < KNN) kr[tid] = -1;

    // ---- Phase A: per-wave 16-smallest approx values over strided 192 ----
    float av[3];
    #pragma unroll
    for (int j = 0; j < 3; ++j) {
        int i = (w * 3 + j) * 64 + lane;
        av[j] = (i < n) ? __half2float(buf_h[(size_t)q * CAP + i]) : 3.4e38f;
    }
    for (int sel = 0; sel < KNN; ++sel) {
        float mv = av[0]; int mc = (lane << 2);
        if (av[1] < mv) { mv = av[1]; mc = (lane << 2) | 1; }
        if (av[2] < mv) { mv = av[2]; mc = (lane << 2) | 2; }
        #pragma unroll
        for (int off = 32; off > 0; off >>= 1) {
            float ov = __shfl_down(mv, off, 64);
            int   oc = __shfl_down(mc, off, 64);
            if (ov < mv || (ov == mv && oc < mc)) { mv = ov; mc = oc; }
        }
        mv = __shfl(mv, 0, 64);
        mc = __shfl(mc, 0, 64);
        if (lane == 0) wk[w * KNN + sel] = mv;
        if (lane == (mc >> 2)) {
            int j0 = mc & 3;
            if (j0 == 0) av[0] = 3.4e38f;
            else if (j0 == 1) av[1] = 3.4e38f;
            else av[2] = 3.4e38f;
        }
    }
    __syncthreads();
    // rank-merge of the 4x16 sorted lists -> global 16th smallest value
    if (tid < 64) {
        float v = wk[tid];
        int rank = 0;
        #pragma unroll 8
        for (int j = 0; j < 64; ++j) {
            float u = wk[j];
            if (u < v || (u == v && j < tid)) ++rank;
        }
        if (rank == KNN - 1) sthr = v + SLACK;
    }
    __syncthreads();
    float thr = sthr;

    // ---- Phase B: compact candidates within the window ----
    for (int i = tid; i < n; i += 256) {
        float h = __half2float(buf_h[(size_t)q * CAP + i]);
        if (h <= thr) {
            int p = atomicAdd(&smcnt, 1);
            keep[p] = buf_i[(size_t)q * CAP + i];
        }
    }
    __syncthreads();
    int m = smcnt;

    // ---- Phase C: exact fp32 distances for kept candidates ----
    const float4* xq = (const float4*)&x[(size_t)q * DIM + sub * 8];
    float4 qa = xq[0], qb = xq[1];
    float x2l = x2v[q];
    for (int base = 0; base < m; base += 16) {
        int i = base + w * 4 + grp;
        if (i < m) {
            int idx = keep[i];
            const float4* tr = (const float4*)&train[(size_t)idx * DIM + sub * 8];
            float4 ta = tr[0], tb4 = tr[1];
            float s = qa.x * ta.x + qa.y * ta.y + qa.z * ta.z + qa.w * ta.w
                    + qb.x * tb4.x + qb.y * tb4.y + qb.z * tb4.z + qb.w * tb4.w;
            s += __shfl_xor(s, 1, 64);
            s += __shfl_xor(s, 2, 64);
            s += __shfl_xor(s, 4, 64);
            s += __shfl_xor(s, 8, 64);
            if (sub == 0) { sd[i] = x2l + t2v[idx] - 2.f * s; si[i] = idx; }
        }
    }
    __syncthreads();

    // ---- Phase D: parallel rank-scatter selection (ranks unique: (d,idx)
    // total order). Each thread ranks its strided elements vs all m. ----
    for (int i = tid; i < m; i += 256) {
        float d = sd[i]; int ix = si[i];
        int rank = 0;
        for (int j = 0; j < m; ++j)
            if (better(sd[j], si[j], d, ix)) ++rank;
        if (rank < KNN) kr[rank] = i;
    }
    __syncthreads();

    // ---- Vote (m >= 16 structurally: all true top-16 pass filter+prune) ----
    if (tid == 0) {
        bool anyzero = false;
        float dist[KNN]; int kidx[KNN];
        #pragma unroll
        for (int j = 0; j < KNN; ++j) {
            int ii = kr[j];
            if (ii >= 0) {
                dist[j] = sqrtf(fmaxf(sd[ii], 0.f));
                kidx[j] = si[ii];
                if (dist[j] == 0.f) anyzero = true;
            } else { dist[j] = -1.f; kidx[j] = -1; }
        }
        float spr[NCLS];
        #pragma unroll
        for (int c = 0; c < NCLS; ++c) spr[c] = 0.f;
        #pragma unroll
        for (int j = 0; j < KNN; ++j) {
            int idxj = kidx[j];
            if (idxj < 0 || idxj >= M_TRAIN) continue;   // sentinel guard
            float wgt = anyzero ? (dist[j] == 0.f ? 1.f : 0.f) : 1.f / dist[j];
            spr[labels[idxj]] += wgt;
        }
        float s = 0.f;
        #pragma unroll
        for (int c = 0; c < NCLS; ++c) s += spr[c];
        if (s == 0.f) s = 1.f;
        float inv = 1.f / s;
        float best = -1.f; int bc = 0;
        #pragma unroll
        for (int c = 0; c < NCLS; ++c) {
            float pv = spr[c] * inv;
            out[NQ + (size_t)q * NCLS + c] = pv;
            if (pv > best) { best = pv; bc = c; }
        }
        out[q] = (float)bc;
    }
}

// ---------------------------------------------------------------------------
extern "C" void kernel_launch(void* const* d_in, const int* in_sizes, int n_in,
                              void* d_out, int out_size, void* d_ws, size_t ws_size,
                              hipStream_t stream) {
    const float* x      = (const float*)d_in[0];
    const float* train  = (const float*)d_in[1];
    const int*   labels = (const int*)d_in[2];
    float* out = (float*)d_out;

    // Byte-exact ws layout, IDENTICAL footprint (26,116,096 B):
    //   t2 401,408 | x2 8,192 | tau 8,192 | cnt 8,192 |
    //   region @425,984: dsub 25,690,112 (dead after knn_select)
    //     -> reused as buf_i 6,291,456 + xb 524,288 + buf_h 3,145,728
    //        (tb is GONE: the filter packs fp32 train in-kernel)
    char* base = (char*)d_ws;
    float*  t2   = (float*)(base);
    float*  x2   = (float*)(base + 401408);
    float*  tau  = (float*)(base + 409600);
    int*    cnt  = (int*)  (base + 417792);
    char*   region = base + 425984;
    __half* dsub = (__half*)region;                        // 25,690,112 B
    int*    bi   = (int*)(region + 12845056);              //  6,291,456 B
    unsigned int* xb = (unsigned int*)(region + 19136512); //    524,288 B
    __half* bh   = (__half*)(region + 19660800);           //  3,145,728 B

    int nrows = M_TRAIN + NQ;
    knn_norms<<<(nrows * 64 + 255) / 256, 256, 0, stream>>>(train, x, t2, x2, cnt);

    dim3 gs(SCH, NQ / MQ);
    knn_sub_mfma<<<gs, 256, 0, stream>>>(x, train, t2, x2, dsub);

    knn_select<<<NQ, 256, 0, stream>>>(dsub, tau);

    // dsub dead from here: xb/bi/bh live in its storage.
    knn_pack_x<<<(NQ * 64) / 256, 256, 0, stream>>>(x, xb);

    knn_filter14<<<NTILE * (NQ / NQT), 256, 0, stream>>>(
        xb, train, t2, x2, tau, bi, (unsigned short*)bh, cnt);

    knn_final<<<NQ, 256, 0, stream>>>(x, train, t2, x2, bi, bh, cnt, labels, out);
}

// Round 18
// 374.702 us; speedup vs baseline: 1.1842x; 1.1842x over previous
//
#include <hip/hip_runtime.h>
#include <hip/hip_fp16.h>
#include <math.h>

#define M_TRAIN 100000
#define NQ 2048
#define DIM 128
#define KNN 16
#define NCLS 10

// Subsample for tau: every 16th train point; padded to 6272 = 49 * 128.
#define S_STRIDE 16
#define S_CNT (M_TRAIN / S_STRIDE)     // 6250
#define S_PAD 6272
#define SCH 49
#define SPC 128
#define TT 64
#define MQ 128
#define QSTR 136                       // LDS row stride in shorts (128 + 8 pad)

// Filter: one block = 64 queries x 128 train rows, one-shot (high TLP).
#define CAP 768
#define TBH 50176                      // rows per half (392 * 128)
#define NTR 128                        // train rows per block
#define NQT 64                         // queries per block
#define MARGIN 3.0f                    // proven in rounds 4-5/8
#define SLACK 7.0f                     // 2*(MARGIN + fp16 quant 0.25) rounded up

using bfrag = __attribute__((ext_vector_type(8))) short;
using cfrag = __attribute__((ext_vector_type(4))) float;

__device__ __forceinline__ bool better(float d1, int i1, float d2, int i2) {
    return (d1 < d2) || (d1 == d2 && i1 < i2);
}

__device__ __forceinline__ unsigned pack_bf16(float a, float b) {
    unsigned ua = __float_as_uint(a), ub = __float_as_uint(b);
    ua += 0x7fffu + ((ua >> 16) & 1u);   // RNE
    ub += 0x7fffu + ((ub >> 16) & 1u);
    return (ua >> 16) | (ub & 0xffff0000u);
}

__device__ __forceinline__ bfrag pack_bf16x8(const float* p) {
    union { unsigned u[4]; bfrag f; } r;
    r.u[0] = pack_bf16(p[0], p[1]);
    r.u[1] = pack_bf16(p[2], p[3]);
    r.u[2] = pack_bf16(p[4], p[5]);
    r.u[3] = pack_bf16(p[6], p[7]);
    return r.f;
}

__device__ __forceinline__ void gload_lds16(const void* g, void* l) {
    __builtin_amdgcn_global_load_lds(
        (const __attribute__((address_space(1))) unsigned int*)g,
        (__attribute__((address_space(3))) unsigned int*)l, 16, 0, 0);
}

// Insert v into the sorted-ascending 16-entry register list (set semantics:
// scan order does not affect the final 16-smallest set).
__device__ __forceinline__ void ins16(float (&bd)[KNN], float v) {
    if (v < bd[KNN - 1]) {
        bd[KNN - 1] = v;
        #pragma unroll
        for (int j = KNN - 1; j >= 1; --j)
            if (bd[j] < bd[j - 1]) { float t = bd[j]; bd[j] = bd[j - 1]; bd[j - 1] = t; }
    }
}

// ---------------------------------------------------------------------------
// Kernel 0: squared norms, one wave per row. Also zeroes cnt (folded dispatch).
__global__ void knn_norms(const float* __restrict__ train,
                          const float* __restrict__ x,
                          float* __restrict__ t2, float* __restrict__ x2,
                          int* __restrict__ cnt) {
    int gid = blockIdx.x * blockDim.x + threadIdx.x;
    if (gid < NQ) cnt[gid] = 0;
    int gw = gid >> 6;
    int lane = threadIdx.x & 63;
    if (gw >= M_TRAIN + NQ) return;
    const float* r = (gw < M_TRAIN) ? (train + (size_t)gw * DIM)
                                    : (x + (size_t)(gw - M_TRAIN) * DIM);
    float a = r[lane];
    float b = r[lane + 64];
    float s = a * a + b * b;
    #pragma unroll
    for (int off = 32; off > 0; off >>= 1)
        s += __shfl_down(s, off, 64);
    if (lane == 0) {
        if (gw < M_TRAIN) t2[gw] = s; else x2[gw - M_TRAIN] = s;
    }
}

// ---------------------------------------------------------------------------
// Kernel 1: MFMA (bf16) approx-d2 over the stride-16 subsample -> fp16 matrix.
// A-frags packed in-register from fp32 x (bit-identical); no Q LDS staging.
__global__ __launch_bounds__(256, 3)
void knn_sub_mfma(const float* __restrict__ x, const float* __restrict__ train,
                  const float* __restrict__ t2, const float* __restrict__ x2,
                  __half* __restrict__ dsub) {
    __shared__ short T[TT * QSTR];
    __shared__ float t2h[TT];
    int tid = threadIdx.x;
    int w = tid >> 6, lane = tid & 63;
    int rquad = lane >> 4, rcol = lane & 15;
    int qBase = blockIdx.y * MQ;
    int cBase = blockIdx.x * SPC;

    // A-frags for this wave's 32 query rows, packed from fp32 x (L2-hot).
    bfrag A[2][4];
    #pragma unroll
    for (int rt = 0; rt < 2; ++rt) {
        int qr = qBase + w * 32 + rt * 16 + rcol;
        #pragma unroll
        for (int ks = 0; ks < 4; ++ks)
            A[rt][ks] = pack_bf16x8(&x[(size_t)qr * DIM + ks * 32 + rquad * 8]);
    }

    float x2r[2][4];
    #pragma unroll
    for (int rt = 0; rt < 2; ++rt)
        #pragma unroll
        for (int reg = 0; reg < 4; ++reg)
            x2r[rt][reg] = x2[qBase + w * 32 + rt * 16 + rquad * 4 + reg];

    const cfrag zero4 = {0.f, 0.f, 0.f, 0.f};
    for (int t = 0; t < 2; ++t) {
        __syncthreads();
        int sBase = cBase + t * TT;
        #pragma unroll
        for (int it = 0; it < 8; ++it) {
            int f = it * 256 + tid;
            int row = f >> 5, c4 = f & 31;
            int sj = sBase + row;
            bool ok = sj < S_CNT;
            float4 v = ok ? ((const float4*)train)[(size_t)sj * S_STRIDE * (DIM / 4) + c4]
                          : make_float4(0.f, 0.f, 0.f, 0.f);
            uint2 p; p.x = pack_bf16(v.x, v.y); p.y = pack_bf16(v.z, v.w);
            *(uint2*)&T[row * QSTR + c4 * 4] = p;
        }
        if (tid < TT) {
            int sj = sBase + tid;
            t2h[tid] = (sj < S_CNT) ? t2[(size_t)sj * S_STRIDE] : 1e30f;
        }
        __syncthreads();

        cfrag acc[2][4];
        #pragma unroll
        for (int ks = 0; ks < 4; ++ks) {
            bfrag B[4];
            #pragma unroll
            for (int ct = 0; ct < 4; ++ct) {
                int n = ct * 16 + rcol;
                B[ct] = *(const bfrag*)&T[n * QSTR + ks * 32 + rquad * 8];
            }
            #pragma unroll
            for (int rt = 0; rt < 2; ++rt)
                #pragma unroll
                for (int ct = 0; ct < 4; ++ct)
                    acc[rt][ct] = (ks == 0)
                        ? __builtin_amdgcn_mfma_f32_16x16x32_bf16(A[rt][0], B[ct], zero4, 0, 0, 0)
                        : __builtin_amdgcn_mfma_f32_16x16x32_bf16(A[rt][ks], B[ct], acc[rt][ct], 0, 0, 0);
        }

        float th[4];
        #pragma unroll
        for (int ct = 0; ct < 4; ++ct) th[ct] = t2h[ct * 16 + rcol];
        #pragma unroll
        for (int rt = 0; rt < 2; ++rt)
            #pragma unroll
            for (int ct = 0; ct < 4; ++ct)
                #pragma unroll
                for (int reg = 0; reg < 4; ++reg) {
                    float d2 = x2r[rt][reg] + th[ct] - 2.f * acc[rt][ct][reg];
                    int qrow = qBase + w * 32 + rt * 16 + rquad * 4 + reg;
                    int col = sBase + ct * 16 + rcol;
                    dsub[(size_t)qrow * S_PAD + col] = __float2half_rn(d2);
                }
    }
}

// ---------------------------------------------------------------------------
// Kernel 2: tau[q] = 16th-smallest value of dsub row q (values only).
// Vectorized uint4 scan (round-15 proven) + barrier-free tournament + merge.
__global__ __launch_bounds__(256)
void knn_select(const __half* __restrict__ dsub, float* __restrict__ tau) {
    __shared__ float wk[64];
    int q = blockIdx.x, tid = threadIdx.x;
    int w = tid >> 6, lane = tid & 63;

    float bd[KNN];
    #pragma unroll
    for (int j = 0; j < KNN; ++j) bd[j] = 3.4e38f;

    const uint4* dv = (const uint4*)(dsub + (size_t)q * S_PAD);  // 784 vec8
    #pragma unroll 1
    for (int v = tid; v < S_PAD / 8; v += 256) {
        uint4 pk = dv[v];
        unsigned wd[4] = {pk.x, pk.y, pk.z, pk.w};
        #pragma unroll
        for (int e = 0; e < 4; ++e) {
            ins16(bd, __half2float(__ushort_as_half((unsigned short)(wd[e] & 0xFFFFu))));
            ins16(bd, __half2float(__ushort_as_half((unsigned short)(wd[e] >> 16))));
        }
    }

    // Per-wave 16-smallest (sorted output), no barriers.
    #pragma unroll 1
    for (int sel = 0; sel < KNN; ++sel) {
        float mv = bd[0]; int ml = lane;
        #pragma unroll
        for (int off = 32; off > 0; off >>= 1) {
            float ov = __shfl_down(mv, off, 64);
            int   ol = __shfl_down(ml, off, 64);
            if (ov < mv || (ov == mv && ol < ml)) { mv = ov; ml = ol; }
        }
        mv = __shfl(mv, 0, 64);
        ml = __shfl(ml, 0, 64);
        if (lane == 0) wk[w * KNN + sel] = mv;
        if (lane == ml) {
            #pragma unroll
            for (int j = 0; j < KNN - 1; ++j) bd[j] = bd[j + 1];
            bd[KNN - 1] = 3.4e38f;
        }
    }
    __syncthreads();
    // Rank merge of 4 sorted 16-lists -> exact 16th smallest value.
    if (tid < 64) {
        float v = wk[tid];
        int rank = 0;
        #pragma unroll 8
        for (int j = 0; j < 64; ++j) {
            float u = wk[j];
            if (u < v || (u == v && j < tid)) ++rank;
        }
        if (rank == KNN - 1) tau[q] = v;
    }
}

// ---------------------------------------------------------------------------
// Kernel 3: fp32 -> bf16 conversion of one train half (pad rows zero-filled).
// Train rows get the 16-byte-granule XOR swizzle baked into the WRITE so the
// filter's linear global_load_lds lands the swizzled layout in LDS.
// h0 launch carries 256 extra blocks that convert the 2048 query rows into a
// LINEAR bf16 buffer xb.
__global__ __launch_bounds__(256)
void knn_convert_bf16(const float* __restrict__ train,
                      unsigned int* __restrict__ tb, int rowBase,
                      const float* __restrict__ x,
                      unsigned int* __restrict__ xb) {
    int b = blockIdx.x;
    if (b >= (TBH * 32) / 256) {                   // x-conversion tail (h0 only)
        int i = (b - (TBH * 32) / 256) * 256 + threadIdx.x;   // 65536 threads
        int row = i >> 5, seg = i & 31;
        float4 v = ((const float4*)x)[(size_t)row * (DIM / 4) + seg];
        uint2 p; p.x = pack_bf16(v.x, v.y); p.y = pack_bf16(v.z, v.w);
        ((uint2*)xb)[(size_t)row * 32 + seg] = p;  // linear bf16[2048][128]
        return;
    }
    int i = b * 256 + threadIdx.x;                 // one thread per 4 floats
    int row = i >> 5, seg = i & 31;                // row in [0, TBH)
    int g = rowBase + row;
    float4 v = (g < M_TRAIN)
        ? ((const float4*)train)[(size_t)g * (DIM / 4) + seg]
        : make_float4(0.f, 0.f, 0.f, 0.f);
    uint2 p; p.x = pack_bf16(v.x, v.y); p.y = pack_bf16(v.z, v.w);
    int off = (seg * 8) ^ ((row & 7) << 4);        // swizzled byte offset in row
    *(uint2*)((char*)tb + (size_t)row * 256 + off) = p;
}

// ---------------------------------------------------------------------------
// Kernel 4: one-shot bf16 MFMA filter (64 queries x 128 train rows, K=128).
// Best-known shell (round-11, 78.5us): DMA staging + A from xb + one barrier
// + 32 MFMA + sparse per-lane epilogue. (256,5) kept from round 13 (neutral).
// Round-17 note: in-kernel fp32 packing (filter14) measured 251us vs this
// path's 157us+22us convert -- the tb pipeline amortizes the fp32->bf16 work
// once per train row vs 32x per tile, and linear DMA avoids ds_write
// conflicts. This shell is the verified local optimum; do not restructure.
__global__ __launch_bounds__(256, 5)
void knn_filter12(const unsigned int* __restrict__ xbb,
                  const short* __restrict__ tbb,
                  const float* __restrict__ t2, const float* __restrict__ x2,
                  const float* __restrict__ tau, int pBase0,
                  int* __restrict__ buf_i, unsigned short* __restrict__ buf_h,
                  int* __restrict__ cnt) {
    __shared__ __align__(16) short T[NTR * DIM];   // 32768 B, single buffer
    int tid = threadIdx.x;
    int w = tid >> 6, lane = tid & 63;
    int rquad = lane >> 4, rcol = lane & 15;

    // XCD-affinity decode (proven): same-tile q-blocks share an XCD.
    int bid = blockIdx.x;
    int xcd = bid & 7, r = bid >> 3;
    int qb = r & 31;
    int nch = xcd + 8 * (r >> 5);          // 0..391, tile index within half
    int qBase = qb * NQT;
    int tbase = pBase0 + nch * NTR;        // global train row base of tile

    // Stage tile: wave w DMAs rows w*32..w*32+31 (8 x 1KB), linear dest.
    const char* gsrc = (const char*)tbb + (size_t)nch * NTR * 256 + w * 8192 + lane * 16;
    char* ldst = (char*)T + w * 8192;
    #pragma unroll
    for (int i = 0; i < 8; ++i)
        gload_lds16(gsrc + i * 1024, ldst + i * 1024);

    // A-frags: direct bf16 loads from xb (overlaps DMA latency).
    bfrag A[4];
    int qrow = qBase + w * 16 + rcol;
    const char* xrow = (const char*)xbb + (size_t)qrow * 256;
    #pragma unroll
    for (int ks = 0; ks < 4; ++ks)
        A[ks] = *(const bfrag*)(xrow + ks * 64 + rquad * 16);

    float RC[4], x2q[4];
    #pragma unroll
    for (int reg = 0; reg < 4; ++reg) {
        int q = qBase + w * 16 + rquad * 4 + reg;
        x2q[reg] = x2[q];
        RC[reg] = 0.5f * (x2q[reg] - tau[q] - MARGIN);
    }
    float th[8];
    #pragma unroll
    for (int ct = 0; ct < 8; ++ct)
        th[ct] = 0.5f * t2[tbase + ct * 16 + rcol];
    __syncthreads();                       // drains DMA (vmcnt) + joins waves

    // Swizzled B reads: row = ct*16+rcol; byte col XOR'd with (rcol&7)<<4.
    int swz = (rcol & 7) << 4;
    int cs[4];
    #pragma unroll
    for (int ks = 0; ks < 4; ++ks)
        cs[ks] = (ks * 64 + rquad * 16) ^ swz;

    const cfrag zero4 = {0.f, 0.f, 0.f, 0.f};
    cfrag acc[8];
    #pragma unroll
    for (int ks = 0; ks < 4; ++ks)
        #pragma unroll
        for (int ct = 0; ct < 8; ++ct) {
            const bfrag B = *(const bfrag*)((const char*)T + (ct * 16 + rcol) * 256 + cs[ks]);
            acc[ct] = (ks == 0)
                ? __builtin_amdgcn_mfma_f32_16x16x32_bf16(A[0], B, zero4, 0, 0, 0)
                : __builtin_amdgcn_mfma_f32_16x16x32_bf16(A[ks], B, acc[ct], 0, 0, 0);
        }

    // ---- Sparse per-lane epilogue ----
    // okm: ct bits whose train row is real (pad only in the very last tile).
    unsigned okm = 0;
    #pragma unroll
    for (int ct = 0; ct < 8; ++ct)
        if (tbase + ct * 16 + rcol < M_TRAIN) okm |= (1u << ct);

    // Per-lane pass masks, one per accumulator row (query).
    unsigned m8[4];
    #pragma unroll
    for (int reg = 0; reg < 4; ++reg) {
        unsigned m = 0;
        #pragma unroll
        for (int ct = 0; ct < 8; ++ct)
            if (acc[ct][reg] >= RC[reg] + th[ct]) m |= (1u << ct);
        m8[reg] = m & okm;
    }

    // Phase 1: independent atomics, only lanes with passes (no result uses).
    int slotR[4];
    #pragma unroll
    for (int reg = 0; reg < 4; ++reg)
        if (m8[reg])
            slotR[reg] = atomicAdd(&cnt[qBase + w * 16 + rquad * 4 + reg],
                                   __popc(m8[reg]));

    // Phase 2: statically-unrolled bit-walk stores (static acc/th indexing).
    #pragma unroll
    for (int reg = 0; reg < 4; ++reg) {
        unsigned m = m8[reg];
        if (m) {
            int q = qBase + w * 16 + rquad * 4 + reg;
            size_t qoff = (size_t)q * CAP;
            int s0 = slotR[reg];
            #pragma unroll
            for (int ct = 0; ct < 8; ++ct)
                if (m & (1u << ct)) {
                    int slot = s0 + __popc(m & ((1u << ct) - 1));
                    if (slot < CAP) {
                        buf_i[qoff + slot] = tbase + ct * 16 + rcol;
                        float d2a = x2q[reg] + 2.f * th[ct] - 2.f * acc[ct][reg];
                        buf_h[qoff + slot] = __half_as_ushort(__float2half_rn(d2a));
                    }
                }
        }
    }
}

// ---------------------------------------------------------------------------
// Kernel 5: approx-pruned exact re-rank + weighted vote.
// Phase A: 16th-smallest approx d2 (per-wave tournament + 64-wide rank merge)
// Phase B: compact candidates with d2a <= kth + SLACK (provably contains the
//          exact top-16 given |d2a - d2| <= MARGIN + fp16 quant)
// Phase C: exact fp32 gather ONLY for kept candidates (4-5x fewer rows)
// Phase D: fully parallel rank-scatter selection (no serial 16-round chain)
__global__ __launch_bounds__(256)
void knn_final(const float* __restrict__ x,
               const float* __restrict__ train,
               const float* __restrict__ t2v,
               const float* __restrict__ x2v,
               const int* __restrict__ buf_i,
               const __half* __restrict__ buf_h,
               const int* __restrict__ cnt,
               const int* __restrict__ labels,
               float* __restrict__ out) {
    __shared__ float sd[CAP];
    __shared__ int   si[CAP];
    __shared__ int   keep[CAP];
    __shared__ float wk[64];
    __shared__ int   kr[KNN];
    __shared__ float sthr;
    __shared__ int   smcnt;
    int q = blockIdx.x;
    int tid = threadIdx.x;
    int w = tid >> 6, lane = tid & 63;
    int grp = lane >> 4, sub = lane & 15;
    int n = cnt[q]; if (n > CAP) n = CAP;
    if (tid == 0) smcnt = 0;
    if (tid < KNN) kr[tid] = -1;

    // ---- Phase A: per-wave 16-smallest approx values over strided 192 ----
    float av[3];
    #pragma unroll
    for (int j = 0; j < 3; ++j) {
        int i = (w * 3 + j) * 64 + lane;
        av[j] = (i < n) ? __half2float(buf_h[(size_t)q * CAP + i]) : 3.4e38f;
    }
    for (int sel = 0; sel < KNN; ++sel) {
        float mv = av[0]; int mc = (lane << 2);
        if (av[1] < mv) { mv = av[1]; mc = (lane << 2) | 1; }
        if (av[2] < mv) { mv = av[2]; mc = (lane << 2) | 2; }
        #pragma unroll
        for (int off = 32; off > 0; off >>= 1) {
            float ov = __shfl_down(mv, off, 64);
            int   oc = __shfl_down(mc, off, 64);
            if (ov < mv || (ov == mv && oc < mc)) { mv = ov; mc = oc; }
        }
        mv = __shfl(mv, 0, 64);
        mc = __shfl(mc, 0, 64);
        if (lane == 0) wk[w * KNN + sel] = mv;
        if (lane == (mc >> 2)) {
            int j0 = mc & 3;
            if (j0 == 0) av[0] = 3.4e38f;
            else if (j0 == 1) av[1] = 3.4e38f;
            else av[2] = 3.4e38f;
        }
    }
    __syncthreads();
    // rank-merge of the 4x16 sorted lists -> global 16th smallest value
    if (tid < 64) {
        float v = wk[tid];
        int rank = 0;
        #pragma unroll 8
        for (int j = 0; j < 64; ++j) {
            float u = wk[j];
            if (u < v || (u == v && j < tid)) ++rank;
        }
        if (rank == KNN - 1) sthr = v + SLACK;
    }
    __syncthreads();
    float thr = sthr;

    // ---- Phase B: compact candidates within the window ----
    for (int i = tid; i < n; i += 256) {
        float h = __half2float(buf_h[(size_t)q * CAP + i]);
        if (h <= thr) {
            int p = atomicAdd(&smcnt, 1);
            keep[p] = buf_i[(size_t)q * CAP + i];
        }
    }
    __syncthreads();
    int m = smcnt;

    // ---- Phase C: exact fp32 distances for kept candidates ----
    const float4* xq = (const float4*)&x[(size_t)q * DIM + sub * 8];
    float4 qa = xq[0], qb = xq[1];
    float x2l = x2v[q];
    for (int base = 0; base < m; base += 16) {
        int i = base + w * 4 + grp;
        if (i < m) {
            int idx = keep[i];
            const float4* tr = (const float4*)&train[(size_t)idx * DIM + sub * 8];
            float4 ta = tr[0], tb4 = tr[1];
            float s = qa.x * ta.x + qa.y * ta.y + qa.z * ta.z + qa.w * ta.w
                    + qb.x * tb4.x + qb.y * tb4.y + qb.z * tb4.z + qb.w * tb4.w;
            s += __shfl_xor(s, 1, 64);
            s += __shfl_xor(s, 2, 64);
            s += __shfl_xor(s, 4, 64);
            s += __shfl_xor(s, 8, 64);
            if (sub == 0) { sd[i] = x2l + t2v[idx] - 2.f * s; si[i] = idx; }
        }
    }
    __syncthreads();

    // ---- Phase D: parallel rank-scatter selection (ranks unique: (d,idx)
    // total order). Each thread ranks its strided elements vs all m. ----
    for (int i = tid; i < m; i += 256) {
        float d = sd[i]; int ix = si[i];
        int rank = 0;
        for (int j = 0; j < m; ++j)
            if (better(sd[j], si[j], d, ix)) ++rank;
        if (rank < KNN) kr[rank] = i;
    }
    __syncthreads();

    // ---- Vote (m >= 16 structurally: all true top-16 pass filter+prune) ----
    if (tid == 0) {
        bool anyzero = false;
        float dist[KNN]; int kidx[KNN];
        #pragma unroll
        for (int j = 0; j < KNN; ++j) {
            int ii = kr[j];
            if (ii >= 0) {
                dist[j] = sqrtf(fmaxf(sd[ii], 0.f));
                kidx[j] = si[ii];
                if (dist[j] == 0.f) anyzero = true;
            } else { dist[j] = -1.f; kidx[j] = -1; }
        }
        float spr[NCLS];
        #pragma unroll
        for (int c = 0; c < NCLS; ++c) spr[c] = 0.f;
        #pragma unroll
        for (int j = 0; j < KNN; ++j) {
            int idxj = kidx[j];
            if (idxj < 0 || idxj >= M_TRAIN) continue;   // sentinel guard
            float wgt = anyzero ? (dist[j] == 0.f ? 1.f : 0.f) : 1.f / dist[j];
            spr[labels[idxj]] += wgt;
        }
        float s = 0.f;
        #pragma unroll
        for (int c = 0; c < NCLS; ++c) s += spr[c];
        if (s == 0.f) s = 1.f;
        float inv = 1.f / s;
        float best = -1.f; int bc = 0;
        #pragma unroll
        for (int c = 0; c < NCLS; ++c) {
            float pv = spr[c] * inv;
            out[NQ + (size_t)q * NCLS + c] = pv;
            if (pv > best) { best = pv; bc = c; }
        }
        out[q] = (float)bc;
    }
}

// ---------------------------------------------------------------------------
extern "C" void kernel_launch(void* const* d_in, const int* in_sizes, int n_in,
                              void* d_out, int out_size, void* d_ws, size_t ws_size,
                              hipStream_t stream) {
    const float* x      = (const float*)d_in[0];
    const float* train  = (const float*)d_in[1];
    const int*   labels = (const int*)d_in[2];
    float* out = (float*)d_out;

    // Byte-exact ws layout, IDENTICAL footprint (26,116,096 B):
    //   t2 401,408 | x2 8,192 | tau 8,192 | cnt 8,192 |
    //   region @425,984: dsub 25,690,112 (dead after knn_select)
    //     -> reused as tb 12,845,056 + buf_i 6,291,456 + xb 524,288
    //        + buf_h 3,145,728 (fp16 approx d2) -> ends at 22,806,528 < dsub end
    char* base = (char*)d_ws;
    float*  t2   = (float*)(base);
    float*  x2   = (float*)(base + 401408);
    float*  tau  = (float*)(base + 409600);
    int*    cnt  = (int*)  (base + 417792);
    char*   region = base + 425984;
    __half* dsub = (__half*)region;                        // 25,690,112 B
    unsigned int* tb = (unsigned int*)region;              // 12,845,056 B (aliases dsub)
    int*    bi   = (int*)(region + 12845056);              //  6,291,456 B
    unsigned int* xb = (unsigned int*)(region + 19136512); //    524,288 B
    __half* bh   = (__half*)(region + 19660800);           //  3,145,728 B

    int nrows = M_TRAIN + NQ;
    knn_norms<<<(nrows * 64 + 255) / 256, 256, 0, stream>>>(train, x, t2, x2, cnt);

    dim3 gs(SCH, NQ / MQ);
    knn_sub_mfma<<<gs, 256, 0, stream>>>(x, train, t2, x2, dsub);

    knn_select<<<NQ, 256, 0, stream>>>(dsub, tau);

    // dsub dead; process the train set in two bf16 halves over its storage.
    // h0's convert also packs x -> xb (256 extra blocks).
    for (int h = 0; h < 2; ++h) {
        int rowBase = h * TBH;
        int cgrid = (TBH * 32) / 256 + (h == 0 ? (NQ * 32) / 256 : 0);
        knn_convert_bf16<<<cgrid, 256, 0, stream>>>(train, tb, rowBase, x, xb);
        knn_filter12<<<(TBH / NTR) * (NQ / NQT), 256, 0, stream>>>(
            xb, (const short*)tb, t2, x2, tau, rowBase, bi, (unsigned short*)bh, cnt);
    }

    knn_final<<<NQ, 256, 0, stream>>>(x, train, t2, x2, bi, bh, cnt, labels, out);
}